// Round 4
// baseline (897.434 us; speedup 1.0000x reference)
//
#include <hip/hip_runtime.h>
#include <stdint.h>

static constexpr int kN = 128;
static constexpr int kTri = (kN * (kN - 1)) / 2;  // strict upper triangle: 8128 cells
static constexpr float kNeg = -9999.0f;
static constexpr float kThresh = -9000.0f;
static constexpr float kArcBonus = 5.0f;

// Strict-upper-triangle index, requires j > i.
__device__ __forceinline__ int trs(int i, int j) {
    return (i * (2 * kN - 1 - i)) / 2 + (j - i - 1);
}

// Charts: s01/s11 (hot: ~2x the reads) live in static LDS (65,024 B <= 64 KiB).
// s00/s10 live in global scratch d_ws (phase-B only), L2-resident.
// OUTPUT IS FP32 (scores raw fp32; backtrace as exact integer-valued floats).
__global__ __launch_bounds__(256) void eisner_dp(
    const float* __restrict__ vinfo,  // [B][N][N] fp32
    float* __restrict__ outS,         // [B][N][N][2][2] fp32 scores
    float* __restrict__ outBT,        // [B][N][N][2][2] fp32 backtrace (integer-valued)
    float* __restrict__ wsCharts)     // [B][2][kTri] fp32: w00, w10
{
    __shared__ float s01s[kTri];
    __shared__ float s11s[kTri];

    const int tid = threadIdx.x;
    const int b = blockIdx.x;
    const float* v = vinfo + (size_t)b * kN * kN;
    float* gS = outS + (size_t)b * kN * kN * 4;
    float* gB = outBT + (size_t)b * kN * kN * 4;
    float* w00 = wsCharts + (size_t)b * 2 * kTri;
    float* w10 = w00 + kTri;

    // ---- init LDS + global charts to NEG (diagonals are implicit 0) ----
    for (int x = tid; x < kTri; x += 256) {
        s01s[x] = kNeg;
        s11s[x] = kNeg;
        w00[x] = kNeg;
        w10[x] = kNeg;
    }

    // ---- init global output: scores = (i==j ? 0 : NEG), backtrace = 0 ----
    float4* gS4 = (float4*)gS;
    float4* gB4 = (float4*)gB;
    const float4 negq = make_float4(kNeg, kNeg, kNeg, kNeg);
    const float4 zeroq = make_float4(0.f, 0.f, 0.f, 0.f);
    for (int c = tid; c < kN * kN; c += 256) {
        const int i = c >> 7, j = c & (kN - 1);
        gS4[c] = (i == j) ? zeroq : negq;
        gB4[c] = zeroq;
    }
    __syncthreads();

    // ---- DP over span width k ----
    for (int k = 1; k < kN; ++k) {
        const int R = kN - k;  // number of active rows (1..127)
        // P = largest power of two with P*R <= 256, clamped to [2, 64]
        int P = 2;
        while (P < 64 && (P << 1) * R <= 256) P <<= 1;
        const int l = tid & (P - 1);
        const int g = tid / P;
        const bool active = g < R;  // uniform within each P-lane group
        const int i = g;
        const int j = g + k;

        // ---- phase A: incomplete spans (0,0) and (1,0), m in [0, k) ----
        float best00 = -3.0e38f, best10 = -3.0e38f;
        int bi00 = 0x7FFFFFFF, bi10 = 0x7FFFFFFF;
        float part00 = kNeg;  // p00 after only the q=i update (lane l==0 computes it)

        if (active) {
            const float vL = v[j * kN + i];
            const float vR = v[i * kN + j];
            for (int m = l; m < k; m += P) {
                const int q = i + m;
                const float a  = (m == 0)     ? 0.0f : s11s[trs(i, q)];      // S[i][q][1][1]
                const float bb = (m == k - 1) ? 0.0f : s01s[trs(q + 1, j)];  // S[q+1][j][0][1]
                const float base = a + bb;
                // faithful fp32, left-associated: max(base + vL + 5.0, NEG)
                const float p00v = fmaxf((base + vL) + kArcBonus, kNeg);
                const float p10v = fmaxf((base + vR) + kArcBonus, kNeg);
                if (m == 0) part00 = (p00v > kThresh) ? p00v : kNeg;
                if (p00v > best00) { best00 = p00v; bi00 = m; }  // strict > keeps earliest m
                if (p10v > best10) { best10 = p10v; bi10 = m; }
            }
        }
        for (int s = P >> 1; s >= 1; s >>= 1) {
            const float o00 = __shfl_xor(best00, s, 64);
            const int   a00 = __shfl_xor(bi00, s, 64);
            const float o10 = __shfl_xor(best10, s, 64);
            const int   a10 = __shfl_xor(bi10, s, 64);
            if (o00 > best00 || (o00 == best00 && a00 < bi00)) { best00 = o00; bi00 = a00; }
            if (o10 > best10 || (o10 == best10 && a10 < bi10)) { best10 = o10; bi10 = a10; }
        }

        // ---- phase B: complete spans (0,1) and (1,1) ----
        // (0,1): m=0 uses part00 (sequential subtlety); m in [1,k): S01[i][q]+S00[q][j]
        // (1,1): m in [1,k): S10[i][q]+S11[q][j]; m=k uses new10 (fully updated (1,0))
        float best01 = -3.0e38f, best11 = -3.0e38f;
        int bi01 = 0x7FFFFFFF, bi11 = 0x7FFFFFFF;
        if (active) {
            if (l == 0) { best01 = part00; bi01 = 0; }
            for (int m = (l == 0) ? P : l; m < k; m += P) {
                const int q = i + m;
                const float p01v = fmaxf(s01s[trs(i, q)] + w00[trs(q, j)], kNeg);
                const float p11v = fmaxf(w10[trs(i, q)] + s11s[trs(q, j)], kNeg);
                if (p01v > best01) { best01 = p01v; bi01 = m; }
                if (p11v > best11) { best11 = p11v; bi11 = m; }
            }
        }
        for (int s = P >> 1; s >= 1; s >>= 1) {
            const float o01 = __shfl_xor(best01, s, 64);
            const int   a01 = __shfl_xor(bi01, s, 64);
            const float o11 = __shfl_xor(best11, s, 64);
            const int   a11 = __shfl_xor(bi11, s, 64);
            if (o01 > best01 || (o01 == best01 && a01 < bi01)) { best01 = o01; bi01 = a01; }
            if (o11 > best11 || (o11 == best11 && a11 < bi11)) { best11 = o11; bi11 = a11; }
        }

        // ---- updates (lane 0 of each active group) ----
        if (active && l == 0) {
            const float new10 = (best10 > kThresh) ? best10 : kNeg;
            if (new10 > best11) { best11 = new10; bi11 = k; }  // q=j candidate; strict > keeps earlier q

            const int cellS = (i * kN + j) * 4;  // + d*2 + c
            const int tIJ = trs(i, j);
            if (best00 > kThresh) {
                w00[tIJ] = best00;
                gS[cellS + 0] = best00;
                gB[cellS + 0] = (float)(i + bi00);
            }
            if (best10 > kThresh) {
                w10[tIJ] = best10;
                gS[cellS + 2] = best10;
                gB[cellS + 2] = (float)(i + bi10);
            }
            if (best01 > kThresh) {
                s01s[tIJ] = best01;
                gS[cellS + 1] = best01;
                gB[cellS + 1] = (float)(i + bi01);
            }
            if (best11 > kThresh) {
                s11s[tIJ] = best11;
                gS[cellS + 3] = best11;
                gB[cellS + 3] = (float)(i + bi11);
            }
        }
        // Barrier orders this step's LDS + global chart writes before
        // next step's reads (compiler drains vmcnt/lgkmcnt before s_barrier).
        __syncthreads();
    }
}

extern "C" void kernel_launch(void* const* d_in, const int* in_sizes, int n_in,
                              void* d_out, int out_size, void* d_ws, size_t ws_size,
                              hipStream_t stream) {
    (void)n_in; (void)out_size; (void)ws_size;
    const float* vinfo = (const float*)d_in[0];  // fp32 [B][N][N]
    const int B = in_sizes[1];                   // b_buffer_size has B elements
    float* outS = (float*)d_out;
    float* outBT = outS + (size_t)B * kN * kN * 4;
    float* wsCharts = (float*)d_ws;              // needs B*2*kTri*4 = ~4.2 MB

    eisner_dp<<<dim3(B), dim3(256), 0, stream>>>(vinfo, outS, outBT, wsCharts);
}

// Round 5
// 565.828 us; speedup vs baseline: 1.5861x; 1.5861x over previous
//
#include <hip/hip_runtime.h>
#include <stdint.h>

static constexpr int kN = 128;
static constexpr int kTri = (kN * (kN - 1)) / 2;  // strict upper triangle: 8128 cells
static constexpr int kThreads = 1024;
static constexpr float kNeg = -9999.0f;
static constexpr float kThresh = -9000.0f;
static constexpr float kArcBonus = 5.0f;

// Strict-upper-triangle index, requires j > i.
__device__ __forceinline__ int trs(int i, int j) {
    return (i * (2 * kN - 1 - i)) / 2 + (j - i - 1);
}
__device__ __forceinline__ int rowBase(int i) {
    return (i * (2 * kN - 1 - i)) / 2;
}

// Charts: s01/s11 (hot) in static LDS (65,024 B); s00/s10 in global scratch (L2).
// Output fp32: scores raw; backtrace as exact integer-valued floats.
__global__ __launch_bounds__(kThreads) void eisner_dp(
    const float* __restrict__ vinfo,  // [B][N][N] fp32
    float* __restrict__ outS,         // [B][N][N][2][2] fp32 scores
    float* __restrict__ outBT,        // [B][N][N][2][2] fp32 backtrace (integer-valued)
    float* __restrict__ wsCharts)     // [B][2][kTri] fp32: w00, w10
{
    __shared__ float s01s[kTri];
    __shared__ float s11s[kTri];

    const int tid = threadIdx.x;
    const int b = blockIdx.x;
    const float* v = vinfo + (size_t)b * kN * kN;
    float* gS = outS + (size_t)b * kN * kN * 4;
    float* gB = outBT + (size_t)b * kN * kN * 4;
    float* w00 = wsCharts + (size_t)b * 2 * kTri;
    float* w10 = w00 + kTri;

    // ---- init LDS + global charts to NEG (diagonals are implicit 0) ----
    for (int x = tid; x < kTri; x += kThreads) {
        s01s[x] = kNeg;
        s11s[x] = kNeg;
        w00[x] = kNeg;
        w10[x] = kNeg;
    }

    // ---- init global output: scores = (i==j ? 0 : NEG), backtrace = 0 ----
    float4* gS4 = (float4*)gS;
    float4* gB4 = (float4*)gB;
    const float4 negq = make_float4(kNeg, kNeg, kNeg, kNeg);
    const float4 zeroq = make_float4(0.f, 0.f, 0.f, 0.f);
    for (int c = tid; c < kN * kN; c += kThreads) {
        const int i = c >> 7, j = c & (kN - 1);
        gS4[c] = (i == j) ? zeroq : negq;
        gB4[c] = zeroq;
    }
    __syncthreads();

    // ---- DP over span width k ----
    for (int k = 1; k < kN; ++k) {
        const int R = kN - k;  // active rows (1..127)
        // P = largest power of two with P*R <= kThreads, clamped to [2, 64]
        int P = 2;
        while (P < 64 && (P << 1) * R <= kThreads) P <<= 1;
        const int l = tid & (P - 1);
        const int g = tid / P;
        const bool active = g < R;  // uniform within each P-lane group
        const int i = g;
        const int j = g + k;

        // ---- fused phases: candidates over split m ----
        // A: (0,0)/(1,0) for m in [0,k): s11[i][q] + s01[q+1][j] + v +- bonus
        // B: (0,1) m in [1,k): s01[i][q] + w00[q][j];  m=0 seeded from part00
        //    (1,1) m in [1,k): w10[i][q] + s11[q][j];  m=k from new10 post-reduce
        float best00 = -3.0e38f, best10 = -3.0e38f;
        float best01 = -3.0e38f, best11 = -3.0e38f;
        int bi00 = 0x7FFFFFFF, bi10 = 0x7FFFFFFF;
        int bi01 = 0x7FFFFFFF, bi11 = 0x7FFFFFFF;
        float part00 = kNeg;  // p00 after only the q=i update (lane l==0 owns m=0)

        if (active) {
            const float vL = v[j * kN + i];
            const float vR = v[i * kN + j];
            const int rbI = rowBase(i);  // trs(i, i+m) = rbI + m - 1
#pragma unroll 4
            for (int m = l; m < k; m += P) {
                const int q = i + m;
                const int tQJ = rowBase(q) + (j - q - 1);  // trs(q, j)
                // phase A operands (row i of s11; column j of s01 shifted)
                const float a  = (m == 0)     ? 0.0f : s11s[rbI + m - 1];
                const float bb = (m == k - 1) ? 0.0f : s01s[tQJ + (kN - 1 - q) - 1];  // trs(q+1,j)
                const float base = a + bb;
                const float p00v = fmaxf((base + vL) + kArcBonus, kNeg);
                const float p10v = fmaxf((base + vR) + kArcBonus, kNeg);
                if (m == 0) part00 = (p00v > kThresh) ? p00v : kNeg;
                if (p00v > best00) { best00 = p00v; bi00 = m; }  // strict > keeps earliest m
                if (p10v > best10) { best10 = p10v; bi10 = m; }
                // phase B (m >= 1 only)
                if (m >= 1) {
                    const float p01v = fmaxf(s01s[rbI + m - 1] + w00[tQJ], kNeg);
                    const float p11v = fmaxf(w10[rbI + m - 1] + s11s[tQJ], kNeg);
                    if (p01v > best01) { best01 = p01v; bi01 = m; }
                    if (p11v > best11) { best11 = p11v; bi11 = m; }
                }
            }
            // seed (0,1) m=0 candidate: index 0 wins ties (first occurrence)
            if (l == 0 && part00 >= best01) { best01 = part00; bi01 = 0; }
        }

        // ---- single butterfly reduction for all four (value, first-index) ----
        for (int s = P >> 1; s >= 1; s >>= 1) {
            const float o00 = __shfl_xor(best00, s, 64);
            const int   a00 = __shfl_xor(bi00, s, 64);
            const float o10 = __shfl_xor(best10, s, 64);
            const int   a10 = __shfl_xor(bi10, s, 64);
            const float o01 = __shfl_xor(best01, s, 64);
            const int   a01 = __shfl_xor(bi01, s, 64);
            const float o11 = __shfl_xor(best11, s, 64);
            const int   a11 = __shfl_xor(bi11, s, 64);
            if (o00 > best00 || (o00 == best00 && a00 < bi00)) { best00 = o00; bi00 = a00; }
            if (o10 > best10 || (o10 == best10 && a10 < bi10)) { best10 = o10; bi10 = a10; }
            if (o01 > best01 || (o01 == best01 && a01 < bi01)) { best01 = o01; bi01 = a01; }
            if (o11 > best11 || (o11 == best11 && a11 < bi11)) { best11 = o11; bi11 = a11; }
        }

        // ---- updates (lane 0 of each active group) ----
        if (active && l == 0) {
            const float new10 = (best10 > kThresh) ? best10 : kNeg;
            if (new10 > best11) { best11 = new10; bi11 = k; }  // q=j; strict > keeps earlier q

            const int cellS = (i * kN + j) * 4;  // + d*2 + c
            const int tIJ = trs(i, j);
            if (best00 > kThresh) {
                w00[tIJ] = best00;
                gS[cellS + 0] = best00;
                gB[cellS + 0] = (float)(i + bi00);
            }
            if (best10 > kThresh) {
                w10[tIJ] = best10;
                gS[cellS + 2] = best10;
                gB[cellS + 2] = (float)(i + bi10);
            }
            if (best01 > kThresh) {
                s01s[tIJ] = best01;
                gS[cellS + 1] = best01;
                gB[cellS + 1] = (float)(i + bi01);
            }
            if (best11 > kThresh) {
                s11s[tIJ] = best11;
                gS[cellS + 3] = best11;
                gB[cellS + 3] = (float)(i + bi11);
            }
        }
        // Barrier orders this step's LDS + global chart writes before
        // next step's reads (compiler drains vmcnt/lgkmcnt before s_barrier).
        __syncthreads();
    }
}

extern "C" void kernel_launch(void* const* d_in, const int* in_sizes, int n_in,
                              void* d_out, int out_size, void* d_ws, size_t ws_size,
                              hipStream_t stream) {
    (void)n_in; (void)out_size; (void)ws_size;
    const float* vinfo = (const float*)d_in[0];  // fp32 [B][N][N]
    const int B = in_sizes[1];                   // b_buffer_size has B elements
    float* outS = (float*)d_out;
    float* outBT = outS + (size_t)B * kN * kN * 4;
    float* wsCharts = (float*)d_ws;              // needs B*2*kTri*4 = ~4.2 MB

    eisner_dp<<<dim3(B), dim3(kThreads), 0, stream>>>(vinfo, outS, outBT, wsCharts);
}

// Round 7
// 491.564 us; speedup vs baseline: 1.8257x; 1.1511x over previous
//
#include <hip/hip_runtime.h>
#include <stdint.h>

static constexpr int kN = 128;
static constexpr int kTri = (kN * (kN - 1)) / 2;  // strict upper triangle: 8128 cells
static constexpr int kThreads = 1024;
static constexpr int kSmallK = 16;   // k <= this: one row per lane, no reduction
static constexpr float kNeg = -9999.0f;
static constexpr float kThresh = -9000.0f;
static constexpr float kArcBonus = 5.0f;

__device__ __forceinline__ int rowBase(int i) { return (i * (2 * kN - 1 - i)) / 2; }
__device__ __forceinline__ int trs(int i, int j) { return rowBase(i) + (j - i - 1); }

// Charts: s01/s11 (hot) in static LDS (65,024 B); s00/s10 in global scratch (L2).
// Output fp32: scores raw; backtrace as exact integer-valued floats.
// NOTE: trs(q+1,j) - trs(q,j) = (kN - q - 1) - 1 = kN - 2 - q  (the r6 bug was +1 off).
__global__ __launch_bounds__(kThreads) void eisner_dp(
    const float* __restrict__ vinfo,  // [B][N][N] fp32
    float* __restrict__ outS,         // [B][N][N][2][2] fp32 scores
    float* __restrict__ outBT,        // [B][N][N][2][2] fp32 backtrace (integer-valued)
    float* __restrict__ wsCharts)     // [B][2][kTri] fp32: w00, w10
{
    __shared__ float s01s[kTri];
    __shared__ float s11s[kTri];

    const int tid = threadIdx.x;
    const int b = blockIdx.x;
    const float* v = vinfo + (size_t)b * kN * kN;
    float* gS = outS + (size_t)b * kN * kN * 4;
    float* gB = outBT + (size_t)b * kN * kN * 4;
    float* w00 = wsCharts + (size_t)b * 2 * kTri;
    float* w10 = w00 + kTri;

    // ---- init LDS + scratch charts to NEG (diagonals are implicit 0) ----
    for (int x = tid; x < kTri; x += kThreads) {
        s01s[x] = kNeg;
        s11s[x] = kNeg;
        w00[x] = kNeg;
        w10[x] = kNeg;
    }
    // ---- init output: scores = (i==j ? 0 : NEG), backtrace = 0 ----
    float4* gS4 = (float4*)gS;
    float4* gB4 = (float4*)gB;
    const float4 negq = make_float4(kNeg, kNeg, kNeg, kNeg);
    const float4 zeroq = make_float4(0.f, 0.f, 0.f, 0.f);
    for (int c = tid; c < kN * kN; c += kThreads) {
        const int i = c >> 7, j = c & (kN - 1);
        gS4[c] = (i == j) ? zeroq : negq;
        gB4[c] = zeroq;
    }
    __syncthreads();

    // ---- DP over span width k ----
    for (int k = 1; k < kN; ++k) {
        const int R = kN - k;  // active rows

        if (k <= kSmallK) {
            // ======== small-k: one row per lane, serial scan, no reduction ========
            const int i = tid;
            if (i < R) {
                const int j = i + k;
                const float vL = v[j * kN + i];
                const float vR = v[i * kN + j];
                const int rbI = rowBase(i);
                float best00 = -3.0e38f, best10 = -3.0e38f, best01 = -3.0e38f, best11 = -3.0e38f;
                int bi00 = 0, bi10 = 0, bi01 = 0, bi11 = 0x7FFFFFFF;
                int q = i;
                int tqj = rbI + k - 1;  // trs(i, j) == trs(q, j) at q=i
#pragma unroll 4
                for (int m = 0; m < k; ++m) {
                    const float a  = (m == 0)     ? 0.0f : s11s[rbI + m - 1];
                    const float bb = (m == k - 1) ? 0.0f : s01s[tqj + (kN - 2) - q];  // trs(q+1, j)
                    const float base = a + bb;
                    const float p00v = fmaxf((base + vL) + kArcBonus, kNeg);
                    const float p10v = fmaxf((base + vR) + kArcBonus, kNeg);
                    if (m == 0) {
                        best00 = p00v; best10 = p10v;
                        best01 = (p00v > kThresh) ? p00v : kNeg;  // part00 seed, m=0
                    } else {
                        if (p00v > best00) { best00 = p00v; bi00 = m; }
                        if (p10v > best10) { best10 = p10v; bi10 = m; }
                        const float p01v = fmaxf(s01s[rbI + m - 1] + w00[tqj], kNeg);
                        const float p11v = fmaxf(w10[rbI + m - 1] + s11s[tqj], kNeg);
                        if (p01v > best01) { best01 = p01v; bi01 = m; }
                        if (p11v > best11) { best11 = p11v; bi11 = m; }
                    }
                    tqj += (kN - 2) - q;  // -> trs(q+1, j)   [FIXED: was kN-1-q]
                    ++q;
                }
                const float new10 = (best10 > kThresh) ? best10 : kNeg;
                if (new10 > best11) { best11 = new10; bi11 = k; }

                const int cellS = (i * kN + j) * 4;
                const int tIJ = rbI + k - 1;
                if (best00 > kThresh) { w00[tIJ] = best00; gS[cellS + 0] = best00; gB[cellS + 0] = (float)(i + bi00); }
                if (best10 > kThresh) { w10[tIJ] = best10; gS[cellS + 2] = best10; gB[cellS + 2] = (float)(i + bi10); }
                if (best01 > kThresh) { s01s[tIJ] = best01; gS[cellS + 1] = best01; gB[cellS + 1] = (float)(i + bi01); }
                if (best11 > kThresh) { s11s[tIJ] = best11; gS[cellS + 3] = best11; gB[cellS + 3] = (float)(i + bi11); }
            }
        } else {
            // ======== chunked groups + value butterfly + ballot argmax ========
            int P = 2, lp = 1;
            while (P < 64 && ((P << 1) * R) <= kThreads) { P <<= 1; ++lp; }
            const int l = tid & (P - 1);
            const int g = tid >> lp;
            const int laneId = tid & 63;
            const bool waveActive = (((tid & ~63) >> lp) < R);  // wave-uniform

            float loc00 = -3.0e38f, loc10 = -3.0e38f, loc01 = -3.0e38f, loc11 = -3.0e38f;
            int bi00 = 0x7FFFFFFF, bi10 = 0x7FFFFFFF, bi01 = 0x7FFFFFFF, bi11 = 0x7FFFFFFF;
            const int i = g;
            const int j = g + k;

            if (waveActive) {
                if (g < R) {
                    const int C = (k + P - 1) >> lp;  // chunk size
                    const int mlo = l * C;
                    const int mhi = (mlo + C < k) ? (mlo + C) : k;
                    if (mlo < mhi) {
                        const float vL = v[j * kN + i];
                        const float vR = v[i * kN + j];
                        const int rbI = rowBase(i);
                        int q = i + mlo;
                        int tqj = rowBase(q) + (j - q - 1);  // trs(q, j)
#pragma unroll 4
                        for (int m = mlo; m < mhi; ++m) {
                            const float a  = (m == 0)     ? 0.0f : s11s[rbI + m - 1];
                            const float bb = (m == k - 1) ? 0.0f : s01s[tqj + (kN - 2) - q];  // trs(q+1,j)
                            const float base = a + bb;
                            const float p00v = fmaxf((base + vL) + kArcBonus, kNeg);
                            const float p10v = fmaxf((base + vR) + kArcBonus, kNeg);
                            if (m == 0) {
                                loc00 = p00v; bi00 = 0;
                                loc10 = p10v; bi10 = 0;
                                loc01 = (p00v > kThresh) ? p00v : kNeg;  // part00 seed
                                bi01 = 0;
                            } else {
                                if (p00v > loc00) { loc00 = p00v; bi00 = m; }
                                if (p10v > loc10) { loc10 = p10v; bi10 = m; }
                                const float p01v = fmaxf(s01s[rbI + m - 1] + w00[tqj], kNeg);
                                const float p11v = fmaxf(w10[rbI + m - 1] + s11s[tqj], kNeg);
                                if (p01v > loc01) { loc01 = p01v; bi01 = m; }
                                if (p11v > loc11) { loc11 = p11v; bi11 = m; }
                            }
                            tqj += (kN - 2) - q;  // -> trs(q+1, j)   [FIXED: was kN-1-q]
                            ++q;
                        }
                    }
                }
                // value-only butterfly (4 DS ops per stage)
                float g00 = loc00, g10 = loc10, g01 = loc01, g11 = loc11;
                for (int s = P >> 1; s >= 1; s >>= 1) {
                    g00 = fmaxf(g00, __shfl_xor(g00, s, 64));
                    g10 = fmaxf(g10, __shfl_xor(g10, s, 64));
                    g01 = fmaxf(g01, __shfl_xor(g01, s, 64));
                    g11 = fmaxf(g11, __shfl_xor(g11, s, 64));
                }
                // earliest-m via ballot (contiguous chunks => lane order == m order)
                const int grpStart = laneId & ~(P - 1);
                const uint64_t gmask =
                    (P == 64) ? ~0ull : (((1ull << P) - 1ull) << grpStart);
                const uint64_t m0 = __ballot(loc00 == g00) & gmask;
                const uint64_t m1 = __ballot(loc10 == g10) & gmask;
                const uint64_t m2 = __ballot(loc01 == g01) & gmask;
                const uint64_t m3 = __ballot(loc11 == g11) & gmask;
                const int r00 = __shfl(bi00, __ffsll((unsigned long long)m0) - 1, 64);
                const int r10 = __shfl(bi10, __ffsll((unsigned long long)m1) - 1, 64);
                const int r01 = __shfl(bi01, __ffsll((unsigned long long)m2) - 1, 64);
                int r11 = __shfl(bi11, __ffsll((unsigned long long)m3) - 1, 64);

                if (g < R && l == 0) {
                    float b11 = g11;
                    const float new10 = (g10 > kThresh) ? g10 : kNeg;
                    if (new10 > b11) { b11 = new10; r11 = k; }

                    const int cellS = (i * kN + j) * 4;
                    const int tIJ = rowBase(i) + k - 1;
                    if (g00 > kThresh) { w00[tIJ] = g00; gS[cellS + 0] = g00; gB[cellS + 0] = (float)(i + r00); }
                    if (g10 > kThresh) { w10[tIJ] = g10; gS[cellS + 2] = g10; gB[cellS + 2] = (float)(i + r10); }
                    if (g01 > kThresh) { s01s[tIJ] = g01; gS[cellS + 1] = g01; gB[cellS + 1] = (float)(i + r01); }
                    if (b11 > kThresh) { s11s[tIJ] = b11; gS[cellS + 3] = b11; gB[cellS + 3] = (float)(i + r11); }
                }
            }
        }
        // Barrier orders this step's LDS + global chart writes before next
        // step's reads (compiler drains vmcnt/lgkmcnt before s_barrier).
        __syncthreads();
    }
}

extern "C" void kernel_launch(void* const* d_in, const int* in_sizes, int n_in,
                              void* d_out, int out_size, void* d_ws, size_t ws_size,
                              hipStream_t stream) {
    (void)n_in; (void)out_size; (void)ws_size;
    const float* vinfo = (const float*)d_in[0];  // fp32 [B][N][N]
    const int B = in_sizes[1];                   // b_buffer_size has B elements
    float* outS = (float*)d_out;
    float* outBT = outS + (size_t)B * kN * kN * 4;
    float* wsCharts = (float*)d_ws;              // needs B*2*kTri*4 = ~4.2 MB

    eisner_dp<<<dim3(B), dim3(kThreads), 0, stream>>>(vinfo, outS, outBT, wsCharts);
}

// Round 8
// 410.778 us; speedup vs baseline: 2.1847x; 1.1967x over previous
//
#include <hip/hip_runtime.h>
#include <stdint.h>

static constexpr int kN = 128;
static constexpr int kTri = (kN * (kN - 1)) / 2;  // strict upper triangle: 8128 cells
static constexpr int kThreads = 1024;
static constexpr int kSmallK = 16;   // k <= this: one row per lane, no reduction
static constexpr float kNeg = -9999.0f;
static constexpr float kThresh = -9000.0f;
static constexpr float kArcBonus = 5.0f;
static constexpr int kDynLds = 4 * kTri * (int)sizeof(float);  // 130,048 B (dynamic LDS)

__device__ __forceinline__ int rowBase(int i) { return (i * (2 * kN - 1 - i)) / 2; }

// All 4 charts in dynamic LDS (130 KB; 1 block/CU — matches our 64-block launch).
// Per step: only ONE global store per finished cell (packed u32 backtrace).
// Scores live in the LDS charts (each cell written exactly once, at k = j-i);
// the epilogue emits gS/gB for the whole [N][N][2][2] tensor, coalesced.
// trs(q+1,j) - trs(q,j) = kN - 2 - q  (incremental column walk).
__global__ __launch_bounds__(kThreads) void eisner_dp(
    const float* __restrict__ vinfo,  // [B][N][N] fp32
    float* __restrict__ outS,         // [B][N][N][2][2] fp32 scores
    float* __restrict__ outBT,        // [B][N][N][2][2] fp32 backtrace (integer-valued)
    uint32_t* __restrict__ btPacked)  // [B][kTri] packed backtrace bytes (d_ws)
{
    extern __shared__ float sm[];
    float* s00s = sm;
    float* s01s = sm + kTri;
    float* s10s = sm + 2 * kTri;
    float* s11s = sm + 3 * kTri;

    const int tid = threadIdx.x;
    const int b = blockIdx.x;
    const float* v = vinfo + (size_t)b * kN * kN;
    uint32_t* wsBT = btPacked + (size_t)b * kTri;

    // ---- init LDS charts to NEG (diagonals are implicit 0 in the loads) ----
    for (int x = tid; x < 4 * kTri; x += kThreads) sm[x] = kNeg;
    __syncthreads();

    // ---- DP over span width k ----
    for (int k = 1; k < kN; ++k) {
        const int R = kN - k;  // active rows

        if (k <= kSmallK) {
            // ======== small-k: one row per lane, serial scan, no reduction ========
            const int i = tid;
            if (i < R) {
                const int j = i + k;
                const float vL = v[j * kN + i];
                const float vR = v[i * kN + j];
                const int rbI = rowBase(i);
                float best00 = -3.0e38f, best10 = -3.0e38f, best01 = -3.0e38f, best11 = -3.0e38f;
                int bi00 = 0, bi10 = 0, bi01 = 0, bi11 = 0x7FFFFFFF;
                int q = i;
                int tqj = rbI + k - 1;  // trs(i, j) == trs(q, j) at q=i
#pragma unroll 4
                for (int m = 0; m < k; ++m) {
                    const float a  = (m == 0)     ? 0.0f : s11s[rbI + m - 1];
                    const float bb = (m == k - 1) ? 0.0f : s01s[tqj + (kN - 2) - q];  // trs(q+1, j)
                    const float base = a + bb;
                    const float p00v = fmaxf((base + vL) + kArcBonus, kNeg);
                    const float p10v = fmaxf((base + vR) + kArcBonus, kNeg);
                    if (m == 0) {
                        best00 = p00v; best10 = p10v;
                        best01 = (p00v > kThresh) ? p00v : kNeg;  // part00 seed, m=0
                    } else {
                        if (p00v > best00) { best00 = p00v; bi00 = m; }
                        if (p10v > best10) { best10 = p10v; bi10 = m; }
                        const float p01v = fmaxf(s01s[rbI + m - 1] + s00s[tqj], kNeg);
                        const float p11v = fmaxf(s10s[rbI + m - 1] + s11s[tqj], kNeg);
                        if (p01v > best01) { best01 = p01v; bi01 = m; }
                        if (p11v > best11) { best11 = p11v; bi11 = m; }
                    }
                    tqj += (kN - 2) - q;  // -> trs(q+1, j)
                    ++q;
                }
                const float new10 = (best10 > kThresh) ? best10 : kNeg;
                if (new10 > best11) { best11 = new10; bi11 = k; }

                const int tIJ = rbI + k - 1;
                uint32_t p = 0;
                if (best00 > kThresh) { s00s[tIJ] = best00; p |= (uint32_t)(i + bi00); }
                if (best01 > kThresh) { s01s[tIJ] = best01; p |= (uint32_t)(i + bi01) << 8; }
                if (best10 > kThresh) { s10s[tIJ] = best10; p |= (uint32_t)(i + bi10) << 16; }
                if (best11 > kThresh) { s11s[tIJ] = best11; p |= (uint32_t)(i + bi11) << 24; }
                wsBT[tIJ] = p;  // single global store per cell
            }
        } else {
            // ======== chunked groups + value butterfly + ballot argmax ========
            int P = 2, lp = 1;
            while (P < 64 && ((P << 1) * R) <= kThreads) { P <<= 1; ++lp; }
            const int l = tid & (P - 1);
            const int g = tid >> lp;
            const int laneId = tid & 63;
            const bool waveActive = (((tid & ~63) >> lp) < R);  // wave-uniform

            float loc00 = -3.0e38f, loc10 = -3.0e38f, loc01 = -3.0e38f, loc11 = -3.0e38f;
            int bi00 = 0x7FFFFFFF, bi10 = 0x7FFFFFFF, bi01 = 0x7FFFFFFF, bi11 = 0x7FFFFFFF;
            const int i = g;
            const int j = g + k;

            if (waveActive) {
                if (g < R) {
                    const int C = (k + P - 1) >> lp;  // chunk size (2..8)
                    const int mlo = l * C;
                    const int mhi = (mlo + C < k) ? (mlo + C) : k;
                    if (mlo < mhi) {
                        const float vL = v[j * kN + i];
                        const float vR = v[i * kN + j];
                        const int rbI = rowBase(i);
                        int q = i + mlo;
                        int tqj = rowBase(q) + (j - q - 1);  // trs(q, j)
#pragma unroll 4
                        for (int m = mlo; m < mhi; ++m) {
                            const float a  = (m == 0)     ? 0.0f : s11s[rbI + m - 1];
                            const float bb = (m == k - 1) ? 0.0f : s01s[tqj + (kN - 2) - q];  // trs(q+1,j)
                            const float base = a + bb;
                            const float p00v = fmaxf((base + vL) + kArcBonus, kNeg);
                            const float p10v = fmaxf((base + vR) + kArcBonus, kNeg);
                            if (m == 0) {
                                loc00 = p00v; bi00 = 0;
                                loc10 = p10v; bi10 = 0;
                                loc01 = (p00v > kThresh) ? p00v : kNeg;  // part00 seed
                                bi01 = 0;
                            } else {
                                if (p00v > loc00) { loc00 = p00v; bi00 = m; }
                                if (p10v > loc10) { loc10 = p10v; bi10 = m; }
                                const float p01v = fmaxf(s01s[rbI + m - 1] + s00s[tqj], kNeg);
                                const float p11v = fmaxf(s10s[rbI + m - 1] + s11s[tqj], kNeg);
                                if (p01v > loc01) { loc01 = p01v; bi01 = m; }
                                if (p11v > loc11) { loc11 = p11v; bi11 = m; }
                            }
                            tqj += (kN - 2) - q;  // -> trs(q+1, j)
                            ++q;
                        }
                    }
                }
                // value-only butterfly (4 DS ops per stage)
                float g00 = loc00, g10 = loc10, g01 = loc01, g11 = loc11;
                for (int s = P >> 1; s >= 1; s >>= 1) {
                    g00 = fmaxf(g00, __shfl_xor(g00, s, 64));
                    g10 = fmaxf(g10, __shfl_xor(g10, s, 64));
                    g01 = fmaxf(g01, __shfl_xor(g01, s, 64));
                    g11 = fmaxf(g11, __shfl_xor(g11, s, 64));
                }
                // earliest-m via ballot (contiguous chunks => lane order == m order;
                // empty lanes hold -3e38 and can never equal the group max >= -9999)
                const int grpStart = laneId & ~(P - 1);
                const uint64_t gmask =
                    (P == 64) ? ~0ull : (((1ull << P) - 1ull) << grpStart);
                const uint64_t m0 = __ballot(loc00 == g00) & gmask;
                const uint64_t m1 = __ballot(loc10 == g10) & gmask;
                const uint64_t m2 = __ballot(loc01 == g01) & gmask;
                const uint64_t m3 = __ballot(loc11 == g11) & gmask;
                const int r00 = __shfl(bi00, __ffsll((unsigned long long)m0) - 1, 64);
                const int r10 = __shfl(bi10, __ffsll((unsigned long long)m1) - 1, 64);
                const int r01 = __shfl(bi01, __ffsll((unsigned long long)m2) - 1, 64);
                int r11 = __shfl(bi11, __ffsll((unsigned long long)m3) - 1, 64);

                if (g < R && l == 0) {
                    float b11 = g11;
                    const float new10 = (g10 > kThresh) ? g10 : kNeg;
                    if (new10 > b11) { b11 = new10; r11 = k; }

                    const int tIJ = rowBase(i) + k - 1;
                    uint32_t p = 0;
                    if (g00 > kThresh) { s00s[tIJ] = g00; p |= (uint32_t)(i + r00); }
                    if (g01 > kThresh) { s01s[tIJ] = g01; p |= (uint32_t)(i + r01) << 8; }
                    if (g10 > kThresh) { s10s[tIJ] = g10; p |= (uint32_t)(i + r10) << 16; }
                    if (b11 > kThresh) { s11s[tIJ] = b11; p |= (uint32_t)(i + r11) << 24; }
                    wsBT[tIJ] = p;  // single global store per cell
                }
            }
        }
        // Barrier orders this step's LDS chart writes (and the lone BT store)
        // before next step's reads.
        __syncthreads();
    }

    // ---- epilogue: emit full [N][N][2][2] scores + backtrace, coalesced ----
    float4* gS4 = (float4*)(outS + (size_t)b * kN * kN * 4);
    float4* gB4 = (float4*)(outBT + (size_t)b * kN * kN * 4);
    const float4 negq = make_float4(kNeg, kNeg, kNeg, kNeg);
    const float4 zeroq = make_float4(0.f, 0.f, 0.f, 0.f);
    for (int c = tid; c < kN * kN; c += kThreads) {
        const int i = c >> 7, j = c & (kN - 1);
        if (i < j) {
            const int t = rowBase(i) + (j - i - 1);
            gS4[c] = make_float4(s00s[t], s01s[t], s10s[t], s11s[t]);
            const uint32_t p = wsBT[t];
            gB4[c] = make_float4((float)(p & 255u), (float)((p >> 8) & 255u),
                                 (float)((p >> 16) & 255u), (float)(p >> 24));
        } else if (i == j) {
            gS4[c] = zeroq;
            gB4[c] = zeroq;
        } else {
            gS4[c] = negq;
            gB4[c] = zeroq;
        }
    }
}

extern "C" void kernel_launch(void* const* d_in, const int* in_sizes, int n_in,
                              void* d_out, int out_size, void* d_ws, size_t ws_size,
                              hipStream_t stream) {
    (void)n_in; (void)out_size; (void)ws_size;
    const float* vinfo = (const float*)d_in[0];  // fp32 [B][N][N]
    const int B = in_sizes[1];                   // b_buffer_size has B elements
    float* outS = (float*)d_out;
    float* outBT = outS + (size_t)B * kN * kN * 4;
    uint32_t* btPacked = (uint32_t*)d_ws;        // needs B*kTri*4 = ~2.1 MB

    // Opt in to >64KB dynamic LDS (host-side, idempotent; proven to work in r2).
    hipFuncSetAttribute(reinterpret_cast<const void*>(eisner_dp),
                        hipFuncAttributeMaxDynamicSharedMemorySize, kDynLds);

    eisner_dp<<<dim3(B), dim3(kThreads), kDynLds, stream>>>(vinfo, outS, outBT, btPacked);
}